// Round 1
// baseline (161.129 us; speedup 1.0000x reference)
//
#include <hip/hip_runtime.h>

typedef unsigned short u16;
typedef float f32x4 __attribute__((ext_vector_type(4)));
typedef unsigned short u16x8 __attribute__((ext_vector_type(8)));
typedef unsigned short u16x4 __attribute__((ext_vector_type(4)));
typedef __bf16 bf16x8 __attribute__((ext_vector_type(8)));

union Frag { u16x8 u; bf16x8 b; };

#define DEVFN static __device__ __forceinline__

DEVFN u16 f2bf(float f) {
  unsigned u = __builtin_bit_cast(unsigned, f);
  u += 0x7FFFu + ((u >> 16) & 1u);
  return (u16)(u >> 16);
}
DEVFN float bf2f(u16 h) {
  return __builtin_bit_cast(float, ((unsigned)h) << 16);
}
DEVFN int bswz(int n, int k) { return k ^ ((((n >> 4) ^ n) & 7) << 3); }

// ---------------- prep: w_qt = w_v @ w_temp (bf16), qbias = w_v @ b_temp,
// ---------------- bf16 copies of w_qkv / w_proj ----------------
__global__ __launch_bounds__(256) void k_prep(
    const float* __restrict__ w_qkv, const float* __restrict__ w_v,
    const float* __restrict__ w_proj, const float* __restrict__ w_temp,
    const float* __restrict__ b_temp,
    u16* __restrict__ w_qt, float* __restrict__ qbias,
    u16* __restrict__ w_qkv_bf, u16* __restrict__ w_proj_bf) {
  __shared__ float wvr[256];
  __shared__ float red[256];
  int t = threadIdx.x, blk = blockIdx.x;
  if (blk < 256) {
    wvr[t] = w_v[blk * 256 + t];
    __syncthreads();
    for (int c = t; c < 512; c += 256) {
      float acc = 0.f;
      for (int m = 0; m < 256; ++m) acc += wvr[m] * w_temp[m * 512 + c];
      w_qt[blk * 512 + c] = f2bf(acc);
    }
    red[t] = wvr[t] * b_temp[t];
    __syncthreads();
    for (int s = 128; s > 0; s >>= 1) {
      if (t < s) red[t] += red[t + s];
      __syncthreads();
    }
    if (t == 0) qbias[blk] = red[0];
  } else {
    int e = (blk - 256) * 256 + t;
    if (e < 512 * 256) w_qkv_bf[e] = f2bf(w_qkv[e]);
    else {
      int e2 = e - 512 * 256;
      w_proj_bf[e2] = f2bf(w_proj[e2]);
    }
  }
}

// ---------------- generic 64x64-tile MFMA GEMM ----------------
// V=0: qsmall = w_qt[256x512] x temp[b][512x256]   -> qsmall[b][p][o] f32
// V=1: kv     = w_qkv[512x256] x x[b][256x4096]    -> k_buf/v_buf [b][h][p][d], v_t [b][h][d][p]
// V=2: out    = w_proj[256x256] x o_buf[b] ([N][K]) + b_proj + x -> d_out f32
template <int V>
__global__ __launch_bounds__(256) void k_gemm(
    const u16* __restrict__ A, const float* __restrict__ Bf,
    const u16* __restrict__ Bh, float* __restrict__ Cf,
    u16* __restrict__ Kb, u16* __restrict__ Vb, u16* __restrict__ Vt,
    const float* __restrict__ bias, const float* __restrict__ Xres) {
  constexpr int M = (V == 1) ? 512 : 256;
  constexpr int N = (V == 0) ? 256 : 4096;
  constexpr int K = (V == 0) ? 512 : 256;
  (void)M;

  const int t = threadIdx.x;
  const int lane = t & 63;
  const int wv = t >> 6;
  const int n0 = blockIdx.x * 64;
  const int m0 = blockIdx.y * 64;
  const int b = blockIdx.z;

  __shared__ __align__(16) u16 lds[2 * 64 * 72];
  u16(*lds_a)[72] = (u16(*)[72])lds;
  u16(*lds_b)[72] = (u16(*)[72])(lds + 64 * 72);

  f32x4 acc[2][2] = {};
  const int mq = (wv >> 1) * 32, nq = (wv & 1) * 32;
  const int lr = lane & 15, lg = lane >> 4;

  for (int k0 = 0; k0 < K; k0 += 64) {
    __syncthreads();
    {  // stage A [m][k]
      int m = t >> 2, c0 = (t & 3) * 16;
      const u16* src = A + (m0 + m) * K + k0 + c0;
      *(u16x8*)&lds_a[m][c0] = *(const u16x8*)src;
      *(u16x8*)&lds_a[m][c0 + 8] = *(const u16x8*)(src + 8);
    }
    if constexpr (V != 2) {  // B from f32 [K][N] source -> lds_b[n][k] (cvt+transpose)
      int k = t >> 2, nn0 = (t & 3) * 16;
      const float* src = Bf + (size_t)b * K * N + (size_t)(k0 + k) * N + n0 + nn0;
#pragma unroll
      for (int i4 = 0; i4 < 4; ++i4) {
        f32x4 v = *(const f32x4*)(src + i4 * 4);
#pragma unroll
        for (int j = 0; j < 4; ++j) {
          int n = nn0 + i4 * 4 + j;
          lds_b[n][bswz(n, k)] = f2bf(v[j]);
        }
      }
    } else {  // B from bf16 [N][K] source
      int n = t >> 2, c0 = (t & 3) * 16;
      const u16* src = Bh + (size_t)b * N * K + (size_t)(n0 + n) * K + k0 + c0;
      u16x8 v0 = *(const u16x8*)src, v1 = *(const u16x8*)(src + 8);
      *(u16x8*)&lds_b[n][bswz(n, c0)] = v0;
      *(u16x8*)&lds_b[n][bswz(n, c0 + 8)] = v1;
    }
    __syncthreads();
#pragma unroll
    for (int kk = 0; kk < 2; ++kk) {
      Frag af[2], bfr[2];
#pragma unroll
      for (int i = 0; i < 2; ++i) {
        af[i].u = *(const u16x8*)&lds_a[mq + 16 * i + lr][kk * 32 + 8 * lg];
        int n = nq + 16 * i + lr;
        bfr[i].u = *(const u16x8*)&lds_b[n][bswz(n, kk * 32 + 8 * lg)];
      }
#pragma unroll
      for (int mi = 0; mi < 2; ++mi)
#pragma unroll
        for (int ni = 0; ni < 2; ++ni)
          acc[mi][ni] = __builtin_amdgcn_mfma_f32_16x16x32_bf16(
              af[mi].b, bfr[ni].b, acc[mi][ni], 0, 0, 0);
    }
  }

  if constexpr (V == 0) {
#pragma unroll
    for (int mi = 0; mi < 2; ++mi)
#pragma unroll
      for (int ni = 0; ni < 2; ++ni) {
        int mbase = m0 + mq + 16 * mi + 4 * lg;
        int n = n0 + nq + 16 * ni + lr;
        *(f32x4*)(Cf + ((size_t)b * 256 + n) * 256 + mbase) = acc[mi][ni];
      }
  } else if constexpr (V == 1) {
#pragma unroll
    for (int mi = 0; mi < 2; ++mi)
#pragma unroll
      for (int ni = 0; ni < 2; ++ni) {
        int mbase = m0 + mq + 16 * mi + 4 * lg;
        int n = n0 + nq + 16 * ni + lr;
        u16x4 pk;
#pragma unroll
        for (int j = 0; j < 4; ++j) pk[j] = f2bf(acc[mi][ni][j]);
        if (mbase < 256) {
          int head = mbase >> 5, d = mbase & 31;
          *(u16x4*)(Kb + ((size_t)(b * 8 + head) * 4096 + n) * 32 + d) = pk;
        } else {
          int mm = mbase - 256;
          int head = mm >> 5, d = mm & 31;
          *(u16x4*)(Vb + ((size_t)(b * 8 + head) * 4096 + n) * 32 + d) = pk;
        }
      }
    if (m0 >= 256) {  // also produce v_t[d][p] via LDS transpose
      __syncthreads();
      float(*lds_t)[68] = (float(*)[68])lds;
#pragma unroll
      for (int mi = 0; mi < 2; ++mi)
#pragma unroll
        for (int ni = 0; ni < 2; ++ni)
#pragma unroll
          for (int j = 0; j < 4; ++j)
            lds_t[mq + 16 * mi + 4 * lg + j][nq + 16 * ni + lr] = acc[mi][ni][j];
      __syncthreads();
      int dloc = t >> 2, nc = (t & 3) * 16;
      int head = ((m0 - 256) >> 5) + (dloc >> 5), d = dloc & 31;
      u16x8 o0, o1;
#pragma unroll
      for (int i = 0; i < 8; ++i) {
        o0[i] = f2bf(lds_t[dloc][nc + i]);
        o1[i] = f2bf(lds_t[dloc][nc + 8 + i]);
      }
      u16* dst = Vt + ((size_t)(b * 8 + head) * 32 + d) * 4096 + n0 + nc;
      *(u16x8*)dst = o0;
      *(u16x8*)(dst + 8) = o1;
    }
  } else {
#pragma unroll
    for (int mi = 0; mi < 2; ++mi)
#pragma unroll
      for (int ni = 0; ni < 2; ++ni) {
        int mbase = m0 + mq + 16 * mi + 4 * lg;
        int n = n0 + nq + 16 * ni + lr;
#pragma unroll
        for (int j = 0; j < 4; ++j) {
          int m = mbase + j;
          size_t off = ((size_t)b * 256 + m) * 4096 + n;
          Cf[off] = acc[mi][ni][j] + bias[m] + Xres[off];
        }
      }
  }
}

// ---------------- bilinear 16x16 -> 64x64 upsample of qsmall, + qbias ----------------
DEVFN void blc(int y, int& i0, int& i1, float& w) {
  float fy = 0.25f * y - 0.375f;
  float ff = floorf(fy);
  w = fy - ff;
  int i = (int)ff;
  i0 = i < 0 ? 0 : i;
  i1 = (i + 1 > 15) ? 15 : i + 1;
}

__global__ __launch_bounds__(256) void k_resize(
    const float* __restrict__ qsmall, const float* __restrict__ qbias,
    u16* __restrict__ Qb) {
  int gid = blockIdx.x * 256 + threadIdx.x;
  int c8 = gid & 31;
  int p = (gid >> 5) & 4095;
  int b = gid >> 17;
  int y = p >> 6, x = p & 63;
  int y0, y1, x0, x1;
  float wy, wx;
  blc(y, y0, y1, wy);
  blc(x, x0, x1, wx);
  const float* base = qsmall + (size_t)b * 65536;
  int o0 = c8 * 8;
  const float* r00 = base + (y0 * 16 + x0) * 256 + o0;
  const float* r01 = base + (y0 * 16 + x1) * 256 + o0;
  const float* r10 = base + (y1 * 16 + x0) * 256 + o0;
  const float* r11 = base + (y1 * 16 + x1) * 256 + o0;
  float w00 = (1 - wy) * (1 - wx), w01 = (1 - wy) * wx;
  float w10 = wy * (1 - wx), w11 = wy * wx;
  u16x8 outv;
#pragma unroll
  for (int i = 0; i < 8; ++i) {
    float v = w00 * r00[i] + w01 * r01[i] + w10 * r10[i] + w11 * r11[i] + qbias[o0 + i];
    outv[i] = f2bf(v);
  }
  int head = o0 >> 5, d = o0 & 31;
  *(u16x8*)(Qb + ((size_t)(b * 8 + head) * 4096 + p) * 32 + d) = outv;
}

// ---------------- MFMA flash attention: heads 2..4 (windows 8/16/32) + row-heads 5..7 ----------------
__global__ __launch_bounds__(256) void k_attn(
    const u16* __restrict__ Qb, const u16* __restrict__ Kb,
    const u16* __restrict__ Vt, u16* __restrict__ Ob) {
  int bid = blockIdx.x;
  int t = threadIdx.x, lane = t & 63, wv = t >> 6;
  int b, head, L, i0, by, bx, lws;
  if (bid < 512) {
    head = 2; b = bid >> 6; int w = bid & 63;
    by = (w >> 3) * 8; bx = (w & 7) * 8; lws = 3; L = 64; i0 = 0;
  } else if (bid < 1024) {
    head = 3; int idx = bid - 512; b = idx >> 6; int r = idx & 63;
    int w = r >> 2; by = (w >> 2) * 16; bx = (w & 3) * 16; lws = 4; L = 256; i0 = (r & 3) * 64;
  } else if (bid < 1536) {
    head = 4; int idx = bid - 1024; b = idx >> 6; int r = idx & 63;
    int w = r >> 4; by = (w >> 1) * 32; bx = (w & 1) * 32; lws = 5; L = 1024; i0 = (r & 15) * 64;
  } else {
    int idx = bid - 1536; b = idx / 192; int r = idx % 192;
    head = 5 + (r >> 6); by = r & 63; bx = 0; lws = 6; L = 64; i0 = 0;
  }
  const int wsm = (1 << lws) - 1;
  const size_t hb = (size_t)(b * 8 + head) * 131072;

  auto mapP = [&](int i) { return ((by + (i >> lws)) << 6) + bx + (i & wsm); };

  int lr = lane & 15, lg = lane >> 4;
  int iq = i0 + wv * 16 + lr;
  Frag qf;
  qf.u = *(const u16x8*)(Qb + hb + (size_t)mapP(iq) * 32 + 8 * lg);

  f32x4 oacc[2] = {};
  float mrun[4], lrun[4];
#pragma unroll
  for (int j = 0; j < 4; ++j) { mrun[j] = -1e30f; lrun[j] = 0.f; }

  __shared__ __align__(16) u16 p_lds[4][16][40];
  __shared__ __align__(16) float o_lds[64][36];

  const float SCL = 0.17677669529663687f;
  const float L2E = 1.44269504088896341f;

  for (int j0 = 0; j0 < L; j0 += 32) {
    Frag kf0, kf1;
    kf0.u = *(const u16x8*)(Kb + hb + (size_t)mapP(j0 + lr) * 32 + 8 * lg);
    kf1.u = *(const u16x8*)(Kb + hb + (size_t)mapP(j0 + 16 + lr) * 32 + 8 * lg);
    f32x4 zz = {};
    f32x4 s0 = __builtin_amdgcn_mfma_f32_16x16x32_bf16(qf.b, kf0.b, zz, 0, 0, 0);
    f32x4 s1 = __builtin_amdgcn_mfma_f32_16x16x32_bf16(qf.b, kf1.b, zz, 0, 0, 0);
    float rx[4], p0[4], p1[4], rs[4];
#pragma unroll
    for (int j = 0; j < 4; ++j) {
      s0[j] *= SCL; s1[j] *= SCL;
      rx[j] = fmaxf(s0[j], s1[j]);
    }
#pragma unroll
    for (int off = 1; off < 16; off <<= 1)
#pragma unroll
      for (int j = 0; j < 4; ++j) rx[j] = fmaxf(rx[j], __shfl_xor(rx[j], off, 64));
#pragma unroll
    for (int j = 0; j < 4; ++j) {
      float mn = fmaxf(mrun[j], rx[j]);
      float rc = exp2f((mrun[j] - mn) * L2E);
      mrun[j] = mn;
      p0[j] = exp2f((s0[j] - mn) * L2E);
      p1[j] = exp2f((s1[j] - mn) * L2E);
      rs[j] = p0[j] + p1[j];
      lrun[j] *= rc;
      oacc[0][j] *= rc;
      oacc[1][j] *= rc;
    }
#pragma unroll
    for (int off = 1; off < 16; off <<= 1)
#pragma unroll
      for (int j = 0; j < 4; ++j) rs[j] += __shfl_xor(rs[j], off, 64);
#pragma unroll
    for (int j = 0; j < 4; ++j) lrun[j] += rs[j];
#pragma unroll
    for (int j = 0; j < 4; ++j) {
      p_lds[wv][4 * lg + j][lr] = f2bf(p0[j]);
      p_lds[wv][4 * lg + j][lr + 16] = f2bf(p1[j]);
    }
    Frag pa;
    pa.u = *(const u16x8*)&p_lds[wv][lr][8 * lg];
    int pv = mapP(j0 + 8 * lg);
    Frag vf0, vf1;
    vf0.u = *(const u16x8*)(Vt + hb + (size_t)lr * 4096 + pv);
    vf1.u = *(const u16x8*)(Vt + hb + (size_t)(16 + lr) * 4096 + pv);
    oacc[0] = __builtin_amdgcn_mfma_f32_16x16x32_bf16(pa.b, vf0.b, oacc[0], 0, 0, 0);
    oacc[1] = __builtin_amdgcn_mfma_f32_16x16x32_bf16(pa.b, vf1.b, oacc[1], 0, 0, 0);
  }

#pragma unroll
  for (int j = 0; j < 4; ++j) {
    float inv = 1.f / lrun[j];
    oacc[0][j] *= inv;
    oacc[1][j] *= inv;
  }
#pragma unroll
  for (int j = 0; j < 4; ++j) {
    o_lds[wv * 16 + 4 * lg + j][lr] = oacc[0][j];
    o_lds[wv * 16 + 4 * lg + j][16 + lr] = oacc[1][j];
  }
  // readback is wave-internal (thread t reads rows of its own wave)
  int qloc = t >> 2, dc = (t & 3) * 8;
  u16x8 outv;
#pragma unroll
  for (int i = 0; i < 8; ++i) outv[i] = f2bf(o_lds[qloc][dc + i]);
  int iqg = i0 + qloc;
  if (head < 5) {
    int p = mapP(iqg);
    *(u16x8*)(Ob + ((size_t)b * 4096 + p) * 256 + head * 32 + dc) = outv;
  } else {
    int n = head - 5;
    int g32 = ((n * 64 + by) << 6) + iqg;
    int m3 = g32 % 3, sp = g32 / 3;
    *(u16x8*)(Ob + ((size_t)b * 4096 + sp) * 256 + 160 + 32 * m3 + dc) = outv;
  }
}

// ---------------- scalar attention for ws=2 (head0) and ws=4 (head1) ----------------
template <int WS>
DEVFN void small_attn_one(const u16* Qb, const u16* Kb, const u16* Vb, u16* Ob,
                          int b, int head, int p) {
  constexpr int L = WS * WS;
  int y = p >> 6, x = p & 63;
  int wy0 = y & ~(WS - 1), wx0 = x & ~(WS - 1);
  const size_t hb = (size_t)(b * 8 + head) * 131072;
  float qr[32];
  const u16* qp = Qb + hb + (size_t)p * 32;
#pragma unroll
  for (int c = 0; c < 4; ++c) {
    u16x8 v = *(const u16x8*)(qp + c * 8);
#pragma unroll
    for (int i = 0; i < 8; ++i) qr[c * 8 + i] = bf2f(v[i]);
  }
  float s[L];
#pragma unroll
  for (int j = 0; j < L; ++j) {
    int kp = (wy0 + j / WS) * 64 + wx0 + (j % WS);
    const u16* kr = Kb + hb + (size_t)kp * 32;
    float acc = 0.f;
#pragma unroll
    for (int c = 0; c < 4; ++c) {
      u16x8 v = *(const u16x8*)(kr + c * 8);
#pragma unroll
      for (int i = 0; i < 8; ++i) acc += qr[c * 8 + i] * bf2f(v[i]);
    }
    s[j] = acc * 0.17677669529663687f;
  }
  float mx = s[0];
#pragma unroll
  for (int j = 1; j < L; ++j) mx = fmaxf(mx, s[j]);
  float sum = 0.f;
#pragma unroll
  for (int j = 0; j < L; ++j) {
    s[j] = exp2f((s[j] - mx) * 1.44269504f);
    sum += s[j];
  }
  float inv = 1.f / sum;
  float o[32];
#pragma unroll
  for (int i = 0; i < 32; ++i) o[i] = 0.f;
#pragma unroll
  for (int j = 0; j < L; ++j) {
    int kp = (wy0 + j / WS) * 64 + wx0 + (j % WS);
    const u16* vr = Vb + hb + (size_t)kp * 32;
    float pj = s[j] * inv;
#pragma unroll
    for (int c = 0; c < 4; ++c) {
      u16x8 v = *(const u16x8*)(vr + c * 8);
#pragma unroll
      for (int i = 0; i < 8; ++i) o[c * 8 + i] += pj * bf2f(v[i]);
    }
  }
  u16* dst = Ob + ((size_t)b * 4096 + p) * 256 + head * 32;
#pragma unroll
  for (int c = 0; c < 4; ++c) {
    u16x8 v;
#pragma unroll
    for (int i = 0; i < 8; ++i) v[i] = f2bf(o[c * 8 + i]);
    *(u16x8*)(dst + c * 8) = v;
  }
}

__global__ __launch_bounds__(256) void k_attn_small(
    const u16* __restrict__ Qb, const u16* __restrict__ Kb,
    const u16* __restrict__ Vb, u16* __restrict__ Ob) {
  int gid = blockIdx.x * 256 + threadIdx.x;
  int head = gid >> 15;
  int idx = gid & 32767;
  int b = idx >> 12, p = idx & 4095;
  if (head == 0) small_attn_one<2>(Qb, Kb, Vb, Ob, b, 0, p);
  else small_attn_one<4>(Qb, Kb, Vb, Ob, b, 1, p);
}

extern "C" void kernel_launch(void* const* d_in, const int* in_sizes, int n_in,
                              void* d_out, int out_size, void* d_ws, size_t ws_size,
                              hipStream_t stream) {
  const float* x = (const float*)d_in[0];
  const float* temp = (const float*)d_in[1];
  const float* w_qkv = (const float*)d_in[2];
  const float* w_v = (const float*)d_in[3];
  const float* w_proj = (const float*)d_in[4];
  const float* b_proj = (const float*)d_in[5];
  const float* w_temp = (const float*)d_in[6];
  const float* b_temp = (const float*)d_in[7];
  (void)in_sizes; (void)n_in; (void)out_size; (void)ws_size;

  char* ws = (char*)d_ws;
  u16* w_qt = (u16*)(ws + 0);              // 262144 B
  u16* w_qkv_bf = (u16*)(ws + 262144);     // 262144 B
  u16* w_proj_bf = (u16*)(ws + 524288);    // 131072 B
  float* qbias = (float*)(ws + 655360);    // 1024 B
  float* qsmall = (float*)(ws + 656384);   // 2097152 B  [b][p16][o]
  u16* q_buf = (u16*)(ws + 2753536);       // 16777216 B [b][h][p][d]
  u16* k_buf = (u16*)(ws + 19530752);      // 16777216 B [b][h][p][d]
  u16* v_buf = (u16*)(ws + 36307968);      // 16777216 B [b][h][p][d]
  u16* v_t = (u16*)(ws + 53085184);        // 16777216 B [b][h][d][p]
  u16* o_buf = (u16*)(ws + 69862400);      // 16777216 B [b][p][c]
  float* out = (float*)d_out;

  k_prep<<<1024, 256, 0, stream>>>(w_qkv, w_v, w_proj, w_temp, b_temp,
                                   w_qt, qbias, w_qkv_bf, w_proj_bf);
  k_gemm<0><<<dim3(4, 4, 8), 256, 0, stream>>>(w_qt, temp, nullptr, qsmall,
                                               nullptr, nullptr, nullptr, nullptr, nullptr);
  k_resize<<<4096, 256, 0, stream>>>(qsmall, qbias, q_buf);
  k_gemm<1><<<dim3(64, 8, 8), 256, 0, stream>>>(w_qkv_bf, x, nullptr, nullptr,
                                                k_buf, v_buf, v_t, nullptr, nullptr);
  k_attn<<<3072, 256, 0, stream>>>(q_buf, k_buf, v_t, o_buf);
  k_attn_small<<<256, 256, 0, stream>>>(q_buf, k_buf, v_buf, o_buf);
  k_gemm<2><<<dim3(64, 4, 8), 256, 0, stream>>>(w_proj_bf, nullptr, o_buf, out,
                                                nullptr, nullptr, nullptr, b_proj, x);
}

// Round 2
// 134.915 us; speedup vs baseline: 1.1943x; 1.1943x over previous
//
#include <hip/hip_runtime.h>

typedef unsigned short u16;
typedef float f32x4 __attribute__((ext_vector_type(4)));
typedef unsigned short u16x8 __attribute__((ext_vector_type(8)));
typedef unsigned short u16x4 __attribute__((ext_vector_type(4)));
typedef __bf16 bf16x8 __attribute__((ext_vector_type(8)));

union Frag { u16x8 u; bf16x8 b; };

#define DEVFN static __device__ __forceinline__

DEVFN u16 f2bf(float f) {
  unsigned u = __builtin_bit_cast(unsigned, f);
  u += 0x7FFFu + ((u >> 16) & 1u);
  return (u16)(u >> 16);
}
DEVFN float bf2f(u16 h) {
  return __builtin_bit_cast(float, ((unsigned)h) << 16);
}
DEVFN int bswz(int n, int k) { return k ^ ((((n >> 4) ^ n) & 7) << 3); }

// combined scale folded into Q: softmax(s*SCALE) == normalize(2^(s*SCALE*log2e))
#define QSC (0.17677669529663687f * 1.44269504088896341f)

// ---------------- prep: w_qt = w_v @ w_temp (bf16), qbias = w_v @ b_temp,
// ---------------- bf16 copies of w_qkv / w_proj ----------------
__global__ __launch_bounds__(256) void k_prep(
    const float* __restrict__ w_qkv, const float* __restrict__ w_v,
    const float* __restrict__ w_proj, const float* __restrict__ w_temp,
    const float* __restrict__ b_temp,
    u16* __restrict__ w_qt, float* __restrict__ qbias,
    u16* __restrict__ w_qkv_bf, u16* __restrict__ w_proj_bf) {
  __shared__ float wvr[256];
  __shared__ float red[256];
  int t = threadIdx.x, blk = blockIdx.x;
  if (blk < 256) {
    wvr[t] = w_v[blk * 256 + t];
    __syncthreads();
    for (int c = t; c < 512; c += 256) {
      float acc = 0.f;
      for (int m = 0; m < 256; ++m) acc += wvr[m] * w_temp[m * 512 + c];
      w_qt[blk * 512 + c] = f2bf(acc);
    }
    red[t] = wvr[t] * b_temp[t];
    __syncthreads();
    for (int s = 128; s > 0; s >>= 1) {
      if (t < s) red[t] += red[t + s];
      __syncthreads();
    }
    if (t == 0) qbias[blk] = red[0];
  } else {
    int e = (blk - 256) * 256 + t;
    if (e < 512 * 256) w_qkv_bf[e] = f2bf(w_qkv[e]);
    else {
      int e2 = e - 512 * 256;
      w_proj_bf[e2] = f2bf(w_proj[e2]);
    }
  }
}

// ---------------- generic 64x64-tile MFMA GEMM ----------------
// V=0: qsmall = w_qt[256x512] x temp[b][512x256]   -> qsmall[b][p][o] f32
// V=1: kv     = w_qkv[512x256] x x[b][256x4096]    -> k_buf/v_buf [b][h][p][d], v_t [b][h][d][p]
// V=2: out    = w_proj[256x256] x o_buf[b] ([N][K]) + b_proj + x -> d_out f32
template <int V>
__global__ __launch_bounds__(256) void k_gemm(
    const u16* __restrict__ A, const float* __restrict__ Bf,
    const u16* __restrict__ Bh, float* __restrict__ Cf,
    u16* __restrict__ Kb, u16* __restrict__ Vb, u16* __restrict__ Vt,
    const float* __restrict__ bias, const float* __restrict__ Xres) {
  constexpr int M = (V == 1) ? 512 : 256;
  constexpr int N = (V == 0) ? 256 : 4096;
  constexpr int K = (V == 0) ? 512 : 256;
  (void)M;

  const int t = threadIdx.x;
  const int lane = t & 63;
  const int wv = t >> 6;
  const int n0 = blockIdx.x * 64;
  const int m0 = blockIdx.y * 64;
  const int b = blockIdx.z;

  __shared__ __align__(16) u16 lds[2 * 64 * 72];
  u16(*lds_a)[72] = (u16(*)[72])lds;
  u16(*lds_b)[72] = (u16(*)[72])(lds + 64 * 72);

  f32x4 acc[2][2] = {};
  const int mq = (wv >> 1) * 32, nq = (wv & 1) * 32;
  const int lr = lane & 15, lg = lane >> 4;

  for (int k0 = 0; k0 < K; k0 += 64) {
    __syncthreads();
    {  // stage A [m][k]
      int m = t >> 2, c0 = (t & 3) * 16;
      const u16* src = A + (m0 + m) * K + k0 + c0;
      *(u16x8*)&lds_a[m][c0] = *(const u16x8*)src;
      *(u16x8*)&lds_a[m][c0 + 8] = *(const u16x8*)(src + 8);
    }
    if constexpr (V != 2) {  // B from f32 [K][N] source -> lds_b[n][k] (cvt+transpose)
      int k = t >> 2, nn0 = (t & 3) * 16;
      const float* src = Bf + (size_t)b * K * N + (size_t)(k0 + k) * N + n0 + nn0;
#pragma unroll
      for (int i4 = 0; i4 < 4; ++i4) {
        f32x4 v = *(const f32x4*)(src + i4 * 4);
#pragma unroll
        for (int j = 0; j < 4; ++j) {
          int n = nn0 + i4 * 4 + j;
          lds_b[n][bswz(n, k)] = f2bf(v[j]);
        }
      }
    } else {  // B from bf16 [N][K] source
      int n = t >> 2, c0 = (t & 3) * 16;
      const u16* src = Bh + (size_t)b * N * K + (size_t)(n0 + n) * K + k0 + c0;
      u16x8 v0 = *(const u16x8*)src, v1 = *(const u16x8*)(src + 8);
      *(u16x8*)&lds_b[n][bswz(n, c0)] = v0;
      *(u16x8*)&lds_b[n][bswz(n, c0 + 8)] = v1;
    }
    __syncthreads();
#pragma unroll
    for (int kk = 0; kk < 2; ++kk) {
      Frag af[2], bfr[2];
#pragma unroll
      for (int i = 0; i < 2; ++i) {
        af[i].u = *(const u16x8*)&lds_a[mq + 16 * i + lr][kk * 32 + 8 * lg];
        int n = nq + 16 * i + lr;
        bfr[i].u = *(const u16x8*)&lds_b[n][bswz(n, kk * 32 + 8 * lg)];
      }
#pragma unroll
      for (int mi = 0; mi < 2; ++mi)
#pragma unroll
        for (int ni = 0; ni < 2; ++ni)
          acc[mi][ni] = __builtin_amdgcn_mfma_f32_16x16x32_bf16(
              af[mi].b, bfr[ni].b, acc[mi][ni], 0, 0, 0);
    }
  }

  if constexpr (V == 0) {
#pragma unroll
    for (int mi = 0; mi < 2; ++mi)
#pragma unroll
      for (int ni = 0; ni < 2; ++ni) {
        int mbase = m0 + mq + 16 * mi + 4 * lg;
        int n = n0 + nq + 16 * ni + lr;
        *(f32x4*)(Cf + ((size_t)b * 256 + n) * 256 + mbase) = acc[mi][ni];
      }
  } else if constexpr (V == 1) {
#pragma unroll
    for (int mi = 0; mi < 2; ++mi)
#pragma unroll
      for (int ni = 0; ni < 2; ++ni) {
        int mbase = m0 + mq + 16 * mi + 4 * lg;
        int n = n0 + nq + 16 * ni + lr;
        u16x4 pk;
#pragma unroll
        for (int j = 0; j < 4; ++j) pk[j] = f2bf(acc[mi][ni][j]);
        if (mbase < 256) {
          int head = mbase >> 5, d = mbase & 31;
          *(u16x4*)(Kb + ((size_t)(b * 8 + head) * 4096 + n) * 32 + d) = pk;
        } else {
          int mm = mbase - 256;
          int head = mm >> 5, d = mm & 31;
          *(u16x4*)(Vb + ((size_t)(b * 8 + head) * 4096 + n) * 32 + d) = pk;
        }
      }
    if (m0 >= 256) {  // also produce v_t[d][p] via LDS transpose
      __syncthreads();
      float(*lds_t)[68] = (float(*)[68])lds;
#pragma unroll
      for (int mi = 0; mi < 2; ++mi)
#pragma unroll
        for (int ni = 0; ni < 2; ++ni)
#pragma unroll
          for (int j = 0; j < 4; ++j)
            lds_t[mq + 16 * mi + 4 * lg + j][nq + 16 * ni + lr] = acc[mi][ni][j];
      __syncthreads();
      int dloc = t >> 2, nc = (t & 3) * 16;
      int head = ((m0 - 256) >> 5) + (dloc >> 5), d = dloc & 31;
      u16x8 o0, o1;
#pragma unroll
      for (int i = 0; i < 8; ++i) {
        o0[i] = f2bf(lds_t[dloc][nc + i]);
        o1[i] = f2bf(lds_t[dloc][nc + 8 + i]);
      }
      u16* dst = Vt + ((size_t)(b * 8 + head) * 32 + d) * 4096 + n0 + nc;
      *(u16x8*)dst = o0;
      *(u16x8*)(dst + 8) = o1;
    }
  } else {
#pragma unroll
    for (int mi = 0; mi < 2; ++mi)
#pragma unroll
      for (int ni = 0; ni < 2; ++ni) {
        int mbase = m0 + mq + 16 * mi + 4 * lg;
        int n = n0 + nq + 16 * ni + lr;
#pragma unroll
        for (int j = 0; j < 4; ++j) {
          int m = mbase + j;
          size_t off = ((size_t)b * 256 + m) * 4096 + n;
          Cf[off] = acc[mi][ni][j] + bias[m] + Xres[off];
        }
      }
  }
}

// ---------------- bilinear 16x16 -> 64x64 upsample of qsmall, + qbias, * QSC ----------------
DEVFN void blc(int y, int& i0, int& i1, float& w) {
  float fy = 0.25f * y - 0.375f;
  float ff = floorf(fy);
  w = fy - ff;
  int i = (int)ff;
  i0 = i < 0 ? 0 : i;
  i1 = (i + 1 > 15) ? 15 : i + 1;
}

__global__ __launch_bounds__(256) void k_resize(
    const float* __restrict__ qsmall, const float* __restrict__ qbias,
    u16* __restrict__ Qb) {
  int gid = blockIdx.x * 256 + threadIdx.x;
  int c8 = gid & 31;
  int p = (gid >> 5) & 4095;
  int b = gid >> 17;
  int y = p >> 6, x = p & 63;
  int y0, y1, x0, x1;
  float wy, wx;
  blc(y, y0, y1, wy);
  blc(x, x0, x1, wx);
  const float* base = qsmall + (size_t)b * 65536;
  int o0 = c8 * 8;
  const float* r00 = base + (y0 * 16 + x0) * 256 + o0;
  const float* r01 = base + (y0 * 16 + x1) * 256 + o0;
  const float* r10 = base + (y1 * 16 + x0) * 256 + o0;
  const float* r11 = base + (y1 * 16 + x1) * 256 + o0;
  float w00 = (1 - wy) * (1 - wx), w01 = (1 - wy) * wx;
  float w10 = wy * (1 - wx), w11 = wy * wx;
  u16x8 outv;
#pragma unroll
  for (int i = 0; i < 8; ++i) {
    float v = w00 * r00[i] + w01 * r01[i] + w10 * r10[i] + w11 * r11[i] + qbias[o0 + i];
    outv[i] = f2bf(v * QSC);
  }
  int head = o0 >> 5, d = o0 & 31;
  *(u16x8*)(Qb + ((size_t)(b * 8 + head) * 4096 + p) * 32 + d) = outv;
}

// ---------------- MFMA attention, swapped-operand, no-LDS ----------------
// wave = 64 queries (4 frags of 16); heads 2..4 windowed, 5..7 per-row.
// No max subtraction (scores are tiny): p = 2^(s), denominator deferred.
__global__ __launch_bounds__(256) void k_attn(
    const u16* __restrict__ Qb, const u16* __restrict__ Kb,
    const u16* __restrict__ Vt, u16* __restrict__ Ob) {
  const int t = threadIdx.x, lane = t & 63, wv = t >> 6;
  const int lr = lane & 15, lg = lane >> 4;
  const int gwid = blockIdx.x * 4 + wv;
  const int u = gwid >> 6;
  const int qb = (gwid & 63) << 6;
  int b, head, lws, L, i0, by, bx;
  if (u < 8) { head = 4; b = u; lws = 5; }
  else if (u < 16) { head = 3; b = u - 8; lws = 4; }
  else if (u < 24) { head = 2; b = u - 16; lws = 3; }
  else { int r = u - 24; head = 5 + (r >> 3); b = r & 7; lws = 6; }
  if (head < 5) {
    L = 1 << (2 * lws);
    int w = qb >> (2 * lws);
    i0 = qb & (L - 1);
    by = (w >> (6 - lws)) << lws;
    bx = (w & ((1 << (6 - lws)) - 1)) << lws;
  } else {
    L = 64; i0 = 0; by = (qb >> 6) & 63; bx = 0;
  }
  const int wsm = (1 << lws) - 1;
  const size_t hb = (size_t)(b * 8 + head) * 131072;
  auto mapP = [&](int i) { return ((by + (i >> lws)) << 6) + bx + (i & wsm); };

  Frag qf[4];
#pragma unroll
  for (int f = 0; f < 4; ++f)
    qf[f].u = *(const u16x8*)(Qb + hb + (size_t)mapP(i0 + 16 * f + lr) * 32 + 8 * lg);

  f32x4 oT[4][2] = {};
  float lsum[4] = {0.f, 0.f, 0.f, 0.f};
  const int addrA = (32 * (lg & 1) + lr) * 4;  // bpermute byte index (w=0,1)
  const int addrB = addrA + 64;                // (w=2,3)
  const bool lo_half = (lg < 2);

  auto chunk = [&](const Frag& k0, const Frag& k1, const Frag& v0, const Frag& v1) {
#pragma unroll
    for (int f = 0; f < 4; ++f) {
      f32x4 zz = {};
      // swapped: D[key][q]; rows=keys, col=query(lr)
      f32x4 s0 = __builtin_amdgcn_mfma_f32_16x16x32_bf16(k0.b, qf[f].b, zz, 0, 0, 0);
      f32x4 s1 = __builtin_amdgcn_mfma_f32_16x16x32_bf16(k1.b, qf[f].b, zz, 0, 0, 0);
      float p[8];
#pragma unroll
      for (int j = 0; j < 4; ++j) {
        p[j] = exp2f(s0[j]);
        p[4 + j] = exp2f(s1[j]);
      }
#pragma unroll
      for (int j = 0; j < 8; ++j) lsum[f] += p[j];
      unsigned pk0, pk1, pk2, pk3;
      asm("v_cvt_pk_bf16_f32 %0, %1, %2" : "=v"(pk0) : "v"(p[0]), "v"(p[1]));
      asm("v_cvt_pk_bf16_f32 %0, %1, %2" : "=v"(pk1) : "v"(p[2]), "v"(p[3]));
      asm("v_cvt_pk_bf16_f32 %0, %1, %2" : "=v"(pk2) : "v"(p[4]), "v"(p[5]));
      asm("v_cvt_pk_bf16_f32 %0, %1, %2" : "=v"(pk3) : "v"(p[6]), "v"(p[7]));
      union { unsigned w[4]; Frag fr; } pb;
      pb.w[0] = (unsigned)__builtin_amdgcn_ds_bpermute(addrA, lo_half ? (int)pk0 : (int)pk2);
      pb.w[1] = (unsigned)__builtin_amdgcn_ds_bpermute(addrA, lo_half ? (int)pk1 : (int)pk3);
      pb.w[2] = (unsigned)__builtin_amdgcn_ds_bpermute(addrB, lo_half ? (int)pk0 : (int)pk2);
      pb.w[3] = (unsigned)__builtin_amdgcn_ds_bpermute(addrB, lo_half ? (int)pk1 : (int)pk3);
      // O^T[d][q]: A = V^T (rows=d), B = P (rows=keys, col=q)
      oT[f][0] = __builtin_amdgcn_mfma_f32_16x16x32_bf16(v0.b, pb.fr.b, oT[f][0], 0, 0, 0);
      oT[f][1] = __builtin_amdgcn_mfma_f32_16x16x32_bf16(v1.b, pb.fr.b, oT[f][1], 0, 0, 0);
    }
  };

  Frag k0A, k1A, v0A, v1A, k0B, k1B, v0B, v1B;
  auto loadKV = [&](int j0, Frag& a, Frag& c, Frag& d, Frag& e) {
    a.u = *(const u16x8*)(Kb + hb + (size_t)mapP(j0 + lr) * 32 + 8 * lg);
    c.u = *(const u16x8*)(Kb + hb + (size_t)mapP(j0 + 16 + lr) * 32 + 8 * lg);
    int pv = mapP(j0 + 8 * lg);
    d.u = *(const u16x8*)(Vt + hb + (size_t)lr * 4096 + pv);
    e.u = *(const u16x8*)(Vt + hb + (size_t)(16 + lr) * 4096 + pv);
  };

  loadKV(0, k0A, k1A, v0A, v1A);
  for (int j0 = 0; j0 < L; j0 += 64) {
    loadKV(j0 + 32, k0B, k1B, v0B, v1B);
    chunk(k0A, k1A, v0A, v1A);
    if (j0 + 64 < L) loadKV(j0 + 64, k0A, k1A, v0A, v1A);
    chunk(k0B, k1B, v0B, v1B);
  }

#pragma unroll
  for (int f = 0; f < 4; ++f) {
    float s = lsum[f];
    s += __shfl_xor(s, 16, 64);
    s += __shfl_xor(s, 32, 64);
    float inv = 1.f / s;
    int q = i0 + 16 * f + lr;
    u16x4 lo, hi;
#pragma unroll
    for (int j = 0; j < 4; ++j) {
      lo[j] = f2bf(oT[f][0][j] * inv);
      hi[j] = f2bf(oT[f][1][j] * inv);
    }
    if (head < 5) {
      int p = mapP(q);
      u16* dst = Ob + ((size_t)b * 4096 + p) * 256 + head * 32;
      *(u16x4*)(dst + 4 * lg) = lo;
      *(u16x4*)(dst + 16 + 4 * lg) = hi;
    } else {
      int n = head - 5;
      int g32 = ((n * 64 + by) << 6) + q;
      int m3 = g32 % 3, sp = g32 / 3;
      u16* dst = Ob + ((size_t)b * 4096 + sp) * 256 + 160 + 32 * m3;
      *(u16x4*)(dst + 4 * lg) = lo;
      *(u16x4*)(dst + 16 + 4 * lg) = hi;
    }
  }
}

// ---------------- scalar attention for ws=2 (head0) and ws=4 (head1) ----------------
template <int WS>
DEVFN void small_attn_one(const u16* Qb, const u16* Kb, const u16* Vb, u16* Ob,
                          int b, int head, int p) {
  constexpr int L = WS * WS;
  int y = p >> 6, x = p & 63;
  int wy0 = y & ~(WS - 1), wx0 = x & ~(WS - 1);
  const size_t hb = (size_t)(b * 8 + head) * 131072;
  float qr[32];
  const u16* qp = Qb + hb + (size_t)p * 32;
#pragma unroll
  for (int c = 0; c < 4; ++c) {
    u16x8 v = *(const u16x8*)(qp + c * 8);
#pragma unroll
    for (int i = 0; i < 8; ++i) qr[c * 8 + i] = bf2f(v[i]);
  }
  float s[L];
#pragma unroll
  for (int j = 0; j < L; ++j) {
    int kp = (wy0 + j / WS) * 64 + wx0 + (j % WS);
    const u16* kr = Kb + hb + (size_t)kp * 32;
    float acc = 0.f;
#pragma unroll
    for (int c = 0; c < 4; ++c) {
      u16x8 v = *(const u16x8*)(kr + c * 8);
#pragma unroll
      for (int i = 0; i < 8; ++i) acc += qr[c * 8 + i] * bf2f(v[i]);
    }
    s[j] = acc;  // Q pre-scaled by SCALE*log2e
  }
  float mx = s[0];
#pragma unroll
  for (int j = 1; j < L; ++j) mx = fmaxf(mx, s[j]);
  float sum = 0.f;
#pragma unroll
  for (int j = 0; j < L; ++j) {
    s[j] = exp2f(s[j] - mx);
    sum += s[j];
  }
  float inv = 1.f / sum;
  float o[32];
#pragma unroll
  for (int i = 0; i < 32; ++i) o[i] = 0.f;
#pragma unroll
  for (int j = 0; j < L; ++j) {
    int kp = (wy0 + j / WS) * 64 + wx0 + (j % WS);
    const u16* vr = Vb + hb + (size_t)kp * 32;
    float pj = s[j] * inv;
#pragma unroll
    for (int c = 0; c < 4; ++c) {
      u16x8 v = *(const u16x8*)(vr + c * 8);
#pragma unroll
      for (int i = 0; i < 8; ++i) o[c * 8 + i] += pj * bf2f(v[i]);
    }
  }
  u16* dst = Ob + ((size_t)b * 4096 + p) * 256 + head * 32;
#pragma unroll
  for (int c = 0; c < 4; ++c) {
    u16x8 v;
#pragma unroll
    for (int i = 0; i < 8; ++i) v[i] = f2bf(o[c * 8 + i]);
    *(u16x8*)(dst + c * 8) = v;
  }
}

__global__ __launch_bounds__(256) void k_attn_small(
    const u16* __restrict__ Qb, const u16* __restrict__ Kb,
    const u16* __restrict__ Vb, u16* __restrict__ Ob) {
  int gid = blockIdx.x * 256 + threadIdx.x;
  int head = gid >> 15;
  int idx = gid & 32767;
  int b = idx >> 12, p = idx & 4095;
  if (head == 0) small_attn_one<2>(Qb, Kb, Vb, Ob, b, 0, p);
  else small_attn_one<4>(Qb, Kb, Vb, Ob, b, 1, p);
}

extern "C" void kernel_launch(void* const* d_in, const int* in_sizes, int n_in,
                              void* d_out, int out_size, void* d_ws, size_t ws_size,
                              hipStream_t stream) {
  const float* x = (const float*)d_in[0];
  const float* temp = (const float*)d_in[1];
  const float* w_qkv = (const float*)d_in[2];
  const float* w_v = (const float*)d_in[3];
  const float* w_proj = (const float*)d_in[4];
  const float* b_proj = (const float*)d_in[5];
  const float* w_temp = (const float*)d_in[6];
  const float* b_temp = (const float*)d_in[7];
  (void)in_sizes; (void)n_in; (void)out_size; (void)ws_size;

  char* ws = (char*)d_ws;
  u16* w_qt = (u16*)(ws + 0);              // 262144 B
  u16* w_qkv_bf = (u16*)(ws + 262144);     // 262144 B
  u16* w_proj_bf = (u16*)(ws + 524288);    // 131072 B
  float* qbias = (float*)(ws + 655360);    // 1024 B
  float* qsmall = (float*)(ws + 656384);   // 2097152 B  [b][p16][o]
  u16* q_buf = (u16*)(ws + 2753536);       // 16777216 B [b][h][p][d]
  u16* k_buf = (u16*)(ws + 19530752);      // 16777216 B [b][h][p][d]
  u16* v_buf = (u16*)(ws + 36307968);      // 16777216 B [b][h][p][d]
  u16* v_t = (u16*)(ws + 53085184);        // 16777216 B [b][h][d][p]
  u16* o_buf = (u16*)(ws + 69862400);      // 16777216 B [b][p][c]
  float* out = (float*)d_out;

  k_prep<<<1024, 256, 0, stream>>>(w_qkv, w_v, w_proj, w_temp, b_temp,
                                   w_qt, qbias, w_qkv_bf, w_proj_bf);
  k_gemm<0><<<dim3(4, 4, 8), 256, 0, stream>>>(w_qt, temp, nullptr, qsmall,
                                               nullptr, nullptr, nullptr, nullptr, nullptr);
  k_resize<<<4096, 256, 0, stream>>>(qsmall, qbias, q_buf);
  k_gemm<1><<<dim3(64, 8, 8), 256, 0, stream>>>(w_qkv_bf, x, nullptr, nullptr,
                                                k_buf, v_buf, v_t, nullptr, nullptr);
  k_attn<<<768, 256, 0, stream>>>(q_buf, k_buf, v_t, o_buf);
  k_attn_small<<<256, 256, 0, stream>>>(q_buf, k_buf, v_buf, o_buf);
  k_gemm<2><<<dim3(64, 4, 8), 256, 0, stream>>>(w_proj_bf, nullptr, o_buf, out,
                                                nullptr, nullptr, nullptr, b_proj, x);
}